// Round 1
// baseline (208.738 us; speedup 1.0000x reference)
//
#include <hip/hip_runtime.h>
#include <hip/hip_bf16.h>
#include <math.h>

#define C    32      // attention dim
#define QD   64      // x1 channels
#define VD   64      // output channels
#define BLK  512     // sliding window block length
#define HALF 256

typedef __attribute__((ext_vector_type(8))) short bf16x8;
typedef __attribute__((ext_vector_type(4))) float f32x4;

static __device__ inline unsigned short f2bf(float x) {
    union { float f; unsigned u; } v; v.f = x;
    unsigned r = v.u + 0x7FFFu + ((v.u >> 16) & 1u);   // RNE
    return (unsigned short)(r >> 16);
}

// pack 2 floats -> one dword holding 2 bf16 (low = a, high = b)
static __device__ inline unsigned pk2(float a, float b) {
    union { __hip_bfloat162 h; unsigned u; } x;
    x.h = __float22bfloat162_rn(make_float2(a, b));
    return x.u;
}

// ---------------- kernel 1: fused QKV projection ----------------
// One pass over x1 (was 3): each thread owns one timestep l and all 96
// output channels (q32 + k32 + v32). x1 fetch 50 MB -> 17 MB.
// qT bf16 (L,32) pre-scaled by 1/sqrt(32); kT bf16 (L,32);
// v2 bf16 tiled: [l>>6][(l>>5)&1][ch][l&31]  (2048 elems / 64-key block)
__global__ __launch_bounds__(256) void qkv_proj(
    const float* __restrict__ x1,
    const float* __restrict__ Wq, const float* __restrict__ bq,
    const float* __restrict__ Wk, const float* __restrict__ bk,
    const float* __restrict__ Wv, const float* __restrict__ bv,
    unsigned short* __restrict__ qT, unsigned short* __restrict__ kT,
    unsigned short* __restrict__ v2, int L)
{
    const int l = blockIdx.x * 256 + threadIdx.x;

    float aq[C], ak[C], av[C];
    #pragma unroll
    for (int o = 0; o < C; ++o) { aq[o] = 0.f; ak[o] = 0.f; av[o] = 0.f; }

    #pragma unroll 4
    for (int c = 0; c < QD; ++c) {
        const float x = x1[(size_t)c * L + l];       // coalesced, read ONCE
        #pragma unroll
        for (int o = 0; o < C; ++o) {
            aq[o] = fmaf(Wq[o * QD + c], x, aq[o]);  // W uniform -> s_load
            ak[o] = fmaf(Wk[o * QD + c], x, ak[o]);
            av[o] = fmaf(Wv[o * QD + c], x, av[o]);
        }
    }

    // q: scaled by 1/sqrt(32), row-contiguous (L,32)
    {
        unsigned short h[C];
        #pragma unroll
        for (int o = 0; o < C; ++o)
            h[o] = f2bf((aq[o] + bq[o]) * 0.17677669529663689f);
        uint4* dst = (uint4*)(qT + (size_t)l * C);
        const uint4* src = (const uint4*)h;
        #pragma unroll
        for (int i = 0; i < 4; ++i) dst[i] = src[i];
    }
    // k: row-contiguous (L,32)
    {
        unsigned short h[C];
        #pragma unroll
        for (int o = 0; o < C; ++o) h[o] = f2bf(ak[o] + bk[o]);
        uint4* dst = (uint4*)(kT + (size_t)l * C);
        const uint4* src = (const uint4*)h;
        #pragma unroll
        for (int i = 0; i < 4; ++i) dst[i] = src[i];
    }
    // v: tiled layout for PV A-frag loads
    {
        unsigned short* dst = v2 + ((size_t)(l >> 6) << 11) + (((l >> 5) & 1) << 10) + (l & 31);
        #pragma unroll
        for (int o = 0; o < C; ++o)
            dst[o << 5] = f2bf(av[o] + bv[o]);
    }
}

// ---------------- kernel 2: MFMA flash attention, split-K waves ----------
// wg = 128 thr = 2 waves covering the SAME 16 queries, alternate 64-key
// chunks (deferred-sum softmax is order-independent). LPT dispatch order,
// XCD-affine. Exactly one causal chunk per tile; full chunks have no
// compares and no clamps (index ranges proven in-bounds).
// Grid MUST be L/16 wgs (one per 16-query tile) — R5 launched half and failed.
// launch_bounds (128,4): (128,8) forced a 64-VGPR cap; the full-chunk body
// wants ~90 live regs (qB+O+S[4]+fm4[4]+wp+kA staging) -> serialization or
// spills. 4 waves/SIMD with full t-unroll ILP instead.
__global__ __launch_bounds__(128, 4) void att_kernel(
    const unsigned short* __restrict__ qT,
    const unsigned short* __restrict__ kT,
    const unsigned short* __restrict__ v2,
    const float* __restrict__ mask,
    const float* __restrict__ Wo, const float* __restrict__ bo,
    float* __restrict__ out, int L)
{
    __shared__ float mrg[64 * 9];

    const int tid  = threadIdx.x;
    const int lane = tid & 63;
    const int h    = tid >> 6;          // wave parity within pair
    const int lo   = lane & 15;
    const int quad = lane >> 4;

    // LPT + XCD affinity: id = (31-s)*128 + w  ->  long waves first, id%8==w%8
    const int id = blockIdx.x;
    const int w  = id & 127;
    const int s  = 31 - (id >> 7);
    const int wq0 = w * BLK + s * 16;

    const int kstart = max(0, w * BLK - HALF);
    const int n      = ((wq0 + 15 - kstart) >> 6) + 1;   // total 64-key chunks
    const int myq    = wq0 + lo;

    // Q B-frag: B[k=c][n=q]
    const bf16x8 qB = *(const bf16x8*)(qT + (size_t)myq * C + quad * 8);

    const f32x4 zero = {0.f, 0.f, 0.f, 0.f};
    f32x4 O0 = zero, O1 = zero;
    float psum = 0.f;

    const int qsl = lo + 16 * ((quad & 1) << 1);

    // ---- full chunks (no causal masking) ----
    for (int j = h; j < n - 1; j += 2) {
        const int kb = kstart + (j << 6);

        f32x4 S[4];
        float4 fm4[4];
        const unsigned short* kp = kT + (size_t)(kb + lo) * C + quad * 8;
        #pragma unroll
        for (int t = 0; t < 4; ++t) {
            const bf16x8 kA = *(const bf16x8*)(kp + (size_t)(t * 16) * C);
            S[t] = __builtin_amdgcn_mfma_f32_16x16x32_bf16(kA, qB, zero, 0, 0, 0);
            fm4[t] = *(const float4*)(mask + kb + t * 16 + quad * 4);
        }

        unsigned wp[4][2];
        #pragma unroll
        for (int t = 0; t < 4; ++t) {
            const float* fmp = (const float*)&fm4[t];
            float p[4];
            #pragma unroll
            for (int r = 0; r < 4; ++r) {
                const float pd = __expf(S[t][r]) * (fmp[r] + 1e-9f);
                psum += pd;
                p[r] = pd * fmp[r];
            }
            wp[t][0] = pk2(p[0], p[1]);
            wp[t][1] = pk2(p[2], p[3]);
        }

        const unsigned short* vbase = v2 + ((size_t)(kb >> 6) << 11);
        #pragma unroll
        for (int g = 0; g < 2; ++g) {
            union { int i[4]; bf16x8 v; } pb;
            #pragma unroll
            for (int i = 0; i < 4; ++i) {
                const int src = qsl + 16 * (i >> 1);
                const int v0 = __shfl((int)wp[2 * g][i & 1], src);
                const int v1 = __shfl((int)wp[2 * g + 1][i & 1], src);
                pb.i[i] = (quad < 2) ? v0 : v1;
            }
            const bf16x8 vA0 = *(const bf16x8*)(vbase + g * 1024 + lo * 32 + quad * 8);
            const bf16x8 vA1 = *(const bf16x8*)(vbase + g * 1024 + (16 + lo) * 32 + quad * 8);
            O0 = __builtin_amdgcn_mfma_f32_16x16x32_bf16(vA0, pb.v, O0, 0, 0, 0);
            O1 = __builtin_amdgcn_mfma_f32_16x16x32_bf16(vA1, pb.v, O1, 0, 0, 0);
        }
    }

    // ---- the single causal chunk (owner: parity of n-1) ----
    if (((n - 1) & 1) == h) {
        const int kb = kstart + ((n - 1) << 6);

        f32x4 S[4];
        float4 fm4[4];
        const unsigned short* kp = kT + (size_t)(kb + lo) * C + quad * 8;
        #pragma unroll
        for (int t = 0; t < 4; ++t) {
            const bf16x8 kA = *(const bf16x8*)(kp + (size_t)(t * 16) * C);
            S[t] = __builtin_amdgcn_mfma_f32_16x16x32_bf16(kA, qB, zero, 0, 0, 0);
            fm4[t] = *(const float4*)(mask + kb + t * 16 + quad * 4);
        }

        unsigned wp[4][2];
        #pragma unroll
        for (int t = 0; t < 4; ++t) {
            const float* fmp = (const float*)&fm4[t];
            float p[4];
            #pragma unroll
            for (int r = 0; r < 4; ++r) {
                const int key = kb + t * 16 + quad * 4 + r;
                const float pd = (key <= myq) ? __expf(S[t][r]) * (fmp[r] + 1e-9f) : 0.f;
                psum += pd;
                p[r] = pd * fmp[r];
            }
            wp[t][0] = pk2(p[0], p[1]);
            wp[t][1] = pk2(p[2], p[3]);
        }

        const unsigned short* vbase = v2 + ((size_t)(kb >> 6) << 11);
        #pragma unroll
        for (int g = 0; g < 2; ++g) {
            union { int i[4]; bf16x8 v; } pb;
            #pragma unroll
            for (int i = 0; i < 4; ++i) {
                const int src = qsl + 16 * (i >> 1);
                const int v0 = __shfl((int)wp[2 * g][i & 1], src);
                const int v1 = __shfl((int)wp[2 * g + 1][i & 1], src);
                pb.i[i] = (quad < 2) ? v0 : v1;
            }
            const bf16x8 vA0 = *(const bf16x8*)(vbase + g * 1024 + lo * 32 + quad * 8);
            const bf16x8 vA1 = *(const bf16x8*)(vbase + g * 1024 + (16 + lo) * 32 + quad * 8);
            O0 = __builtin_amdgcn_mfma_f32_16x16x32_bf16(vA0, pb.v, O0, 0, 0, 0);
            O1 = __builtin_amdgcn_mfma_f32_16x16x32_bf16(vA1, pb.v, O1, 0, 0, 0);
        }
    }

    // ---- merge wave1 partials into wave0 ----
    if (h == 1) {
        #pragma unroll
        for (int r = 0; r < 4; ++r) {
            mrg[lane * 9 + r]     = O0[r];
            mrg[lane * 9 + 4 + r] = O1[r];
        }
        mrg[lane * 9 + 8] = psum;
    }
    __syncthreads();
    if (h == 1) return;

    #pragma unroll
    for (int r = 0; r < 4; ++r) {
        O0[r] += mrg[lane * 9 + r];
        O1[r] += mrg[lane * 9 + 4 + r];
    }
    psum += mrg[lane * 9 + 8];

    // ---- denominator across quads for each query col ----
    float dsum = psum;
    dsum += __shfl_xor(dsum, 16);
    dsum += __shfl_xor(dsum, 32);
    const float inv = 1.f / dsum;

    // ---- epilogue: T = relu(O^T*inv) -> B-layout via quad-permute ----
    unsigned tw[2][2];
    tw[0][0] = pk2(fmaxf(O0[0] * inv, 0.f), fmaxf(O0[1] * inv, 0.f));
    tw[0][1] = pk2(fmaxf(O0[2] * inv, 0.f), fmaxf(O0[3] * inv, 0.f));
    tw[1][0] = pk2(fmaxf(O1[0] * inv, 0.f), fmaxf(O1[1] * inv, 0.f));
    tw[1][1] = pk2(fmaxf(O1[2] * inv, 0.f), fmaxf(O1[3] * inv, 0.f));

    union { int i[4]; bf16x8 v; } tb;
    #pragma unroll
    for (int i = 0; i < 4; ++i) {
        const int src = qsl + 16 * (i >> 1);
        const int v0 = __shfl((int)tw[0][i & 1], src);
        const int v1 = __shfl((int)tw[1][i & 1], src);
        tb.i[i] = (quad < 2) ? v0 : v1;
    }

    const float mk = mask[myq];
    #pragma unroll
    for (int t = 0; t < 4; ++t) {
        float wtmp[8];
        *(float4*)&wtmp[0] = *(const float4*)(Wo + (size_t)(t * 16 + lo) * C + quad * 8);
        *(float4*)&wtmp[4] = *(const float4*)(Wo + (size_t)(t * 16 + lo) * C + quad * 8 + 4);
        union { unsigned u[4]; bf16x8 v; } wo;
        #pragma unroll
        for (int i = 0; i < 4; ++i) wo.u[i] = pk2(wtmp[2 * i], wtmp[2 * i + 1]);
        const f32x4 R = __builtin_amdgcn_mfma_f32_16x16x32_bf16(wo.v, tb.v, zero, 0, 0, 0);
        const float4 bo4 = *(const float4*)(bo + t * 16 + quad * 4);
        const float* bop = (const float*)&bo4;
        #pragma unroll
        for (int r = 0; r < 4; ++r)
            out[(size_t)(t * 16 + quad * 4 + r) * L + myq] = (R[r] + bop[r]) * mk;
    }
}

extern "C" void kernel_launch(void* const* d_in, const int* in_sizes, int n_in,
                              void* d_out, int out_size, void* d_ws, size_t ws_size,
                              hipStream_t stream)
{
    const float* x1   = (const float*)d_in[0];
    // d_in[1] = x2 : unused (encoder stage)
    const float* mask = (const float*)d_in[2];
    const float* Wq   = (const float*)d_in[3];
    const float* bq   = (const float*)d_in[4];
    const float* Wk   = (const float*)d_in[5];
    const float* bk   = (const float*)d_in[6];
    const float* Wv   = (const float*)d_in[7];
    const float* bv   = (const float*)d_in[8];
    const float* Wo   = (const float*)d_in[9];
    const float* bo   = (const float*)d_in[10];
    float* out = (float*)d_out;

    const int L = in_sizes[0] / QD;                  // 65536
    unsigned short* qT = (unsigned short*)d_ws;      // L*32 bf16
    unsigned short* kT = qT + (size_t)L * C;         // L*32 bf16
    unsigned short* v2 = kT + (size_t)L * C;         // L*32 bf16 (tiled)

    hipLaunchKernelGGL(qkv_proj, dim3(L / 256), dim3(256), 0, stream,
                       x1, Wq, bq, Wk, bk, Wv, bv, qT, kT, v2, L);

    // one wg per 16-query tile: L/16 = 4096 wgs (2 waves each, split-K)
    hipLaunchKernelGGL(att_kernel, dim3(L / 16), dim3(128), 0, stream,
                       qT, kT, v2, mask, Wo, bo, out, L);
}

// Round 3
// 178.425 us; speedup vs baseline: 1.1699x; 1.1699x over previous
//
#include <hip/hip_runtime.h>
#include <hip/hip_bf16.h>
#include <math.h>

#define C    32      // attention dim
#define QD   64      // x1 channels
#define VD   64      // output channels
#define BLK  512     // sliding window block length
#define HALF 256

typedef __attribute__((ext_vector_type(8))) short bf16x8;
typedef __attribute__((ext_vector_type(4))) float f32x4;

static __device__ inline unsigned short f2bf(float x) {
    union { float f; unsigned u; } v; v.f = x;
    unsigned r = v.u + 0x7FFFu + ((v.u >> 16) & 1u);   // RNE
    return (unsigned short)(r >> 16);
}

// pack 2 floats -> one dword holding 2 bf16 (low = a, high = b)
static __device__ inline unsigned pk2(float a, float b) {
    union { __hip_bfloat162 h; unsigned u; } x;
    x.h = __float22bfloat162_rn(make_float2(a, b));
    return x.u;
}

// ---------------- kernel 1: QKV projection, sequential kind loop ----------
// R1 lesson: fusing q+k+v into 96 live accumulators spilled (VGPR capped at
// 60 by the allocator heuristic) -> 96 us/dispatch of scratch thrash.
// Fix: ONE dispatch, but kind=0..2 as a RUNTIME loop (#pragma unroll 1 so
// the compiler cannot re-fuse the passes). 32 accumulators live at a time.
// x1 re-reads (passes 2,3) hit L1/L2: block footprint 64 KB, and x1 is
// LLC-resident across iterations (R1 FETCH_SIZE 8.5 MB < x1's 16.7 MB).
// qT bf16 (L,32) pre-scaled by 1/sqrt(32); kT bf16 (L,32);
// v2 bf16 tiled: [l>>6][(l>>5)&1][ch][l&31]  (2048 elems / 64-key block)
__global__ __launch_bounds__(256) void qkv_proj(
    const float* __restrict__ x1,
    const float* __restrict__ Wq, const float* __restrict__ bq,
    const float* __restrict__ Wk, const float* __restrict__ bk,
    const float* __restrict__ Wv, const float* __restrict__ bv,
    unsigned short* __restrict__ qT, unsigned short* __restrict__ kT,
    unsigned short* __restrict__ v2, int L)
{
    const int l = blockIdx.x * 256 + threadIdx.x;

    #pragma unroll 1
    for (int kind = 0; kind < 3; ++kind) {
        // uniform (scalar) selects — no runtime-indexed pointer array
        const float* __restrict__ W = (kind == 0) ? Wq : ((kind == 1) ? Wk : Wv);
        const float* __restrict__ b = (kind == 0) ? bq : ((kind == 1) ? bk : bv);

        float acc[C];
        #pragma unroll
        for (int o = 0; o < C; ++o) acc[o] = 0.f;

        #pragma unroll 4
        for (int c = 0; c < QD; ++c) {
            const float x = x1[(size_t)c * L + l];       // coalesced; L1/L2-hot on passes 2,3
            #pragma unroll
            for (int o = 0; o < C; ++o)
                acc[o] = fmaf(W[o * QD + c], x, acc[o]); // W uniform -> s_load
        }

        if (kind == 2) {
            unsigned short* dst = v2 + ((size_t)(l >> 6) << 11) + (((l >> 5) & 1) << 10) + (l & 31);
            #pragma unroll
            for (int o = 0; o < C; ++o)
                dst[o << 5] = f2bf(acc[o] + b[o]);
        } else {
            const float s = (kind == 0) ? 0.17677669529663689f : 1.0f;
            unsigned short hbuf[C];
            #pragma unroll
            for (int o = 0; o < C; ++o) hbuf[o] = f2bf((acc[o] + b[o]) * s);
            unsigned short* base = ((kind == 0) ? qT : kT) + (size_t)l * C;
            uint4* dst = (uint4*)base;
            const uint4* src = (const uint4*)hbuf;
            #pragma unroll
            for (int i = 0; i < 4; ++i) dst[i] = src[i];
        }
    }
}

// ---------------- kernel 2: MFMA flash attention, split-K waves ----------
// wg = 128 thr = 2 waves covering the SAME 16 queries, alternate 64-key
// chunks (deferred-sum softmax is order-independent). LPT dispatch order,
// XCD-affine. Exactly one causal chunk per tile; full chunks have no
// compares and no clamps (index ranges proven in-bounds).
// Grid MUST be L/16 wgs (one per 16-query tile) — R5 launched half and failed.
// launch_bounds (128,4): (128,8) forced a 64-VGPR cap; the full-chunk body
// wants ~90 live regs (qB+O+S[4]+fm4[4]+wp+kA staging) -> serialization or
// spills. 4 waves/SIMD with full t-unroll ILP instead.
__global__ __launch_bounds__(128, 4) void att_kernel(
    const unsigned short* __restrict__ qT,
    const unsigned short* __restrict__ kT,
    const unsigned short* __restrict__ v2,
    const float* __restrict__ mask,
    const float* __restrict__ Wo, const float* __restrict__ bo,
    float* __restrict__ out, int L)
{
    __shared__ float mrg[64 * 9];

    const int tid  = threadIdx.x;
    const int lane = tid & 63;
    const int h    = tid >> 6;          // wave parity within pair
    const int lo   = lane & 15;
    const int quad = lane >> 4;

    // LPT + XCD affinity: id = (31-s)*128 + w  ->  long waves first, id%8==w%8
    const int id = blockIdx.x;
    const int w  = id & 127;
    const int s  = 31 - (id >> 7);
    const int wq0 = w * BLK + s * 16;

    const int kstart = max(0, w * BLK - HALF);
    const int n      = ((wq0 + 15 - kstart) >> 6) + 1;   // total 64-key chunks
    const int myq    = wq0 + lo;

    // Q B-frag: B[k=c][n=q]
    const bf16x8 qB = *(const bf16x8*)(qT + (size_t)myq * C + quad * 8);

    const f32x4 zero = {0.f, 0.f, 0.f, 0.f};
    f32x4 O0 = zero, O1 = zero;
    float psum = 0.f;

    const int qsl = lo + 16 * ((quad & 1) << 1);

    // ---- full chunks (no causal masking) ----
    for (int j = h; j < n - 1; j += 2) {
        const int kb = kstart + (j << 6);

        f32x4 S[4];
        float4 fm4[4];
        const unsigned short* kp = kT + (size_t)(kb + lo) * C + quad * 8;
        #pragma unroll
        for (int t = 0; t < 4; ++t) {
            const bf16x8 kA = *(const bf16x8*)(kp + (size_t)(t * 16) * C);
            S[t] = __builtin_amdgcn_mfma_f32_16x16x32_bf16(kA, qB, zero, 0, 0, 0);
            fm4[t] = *(const float4*)(mask + kb + t * 16 + quad * 4);
        }

        unsigned wp[4][2];
        #pragma unroll
        for (int t = 0; t < 4; ++t) {
            const float* fmp = (const float*)&fm4[t];
            float p[4];
            #pragma unroll
            for (int r = 0; r < 4; ++r) {
                const float pd = __expf(S[t][r]) * (fmp[r] + 1e-9f);
                psum += pd;
                p[r] = pd * fmp[r];
            }
            wp[t][0] = pk2(p[0], p[1]);
            wp[t][1] = pk2(p[2], p[3]);
        }

        const unsigned short* vbase = v2 + ((size_t)(kb >> 6) << 11);
        #pragma unroll
        for (int g = 0; g < 2; ++g) {
            union { int i[4]; bf16x8 v; } pb;
            #pragma unroll
            for (int i = 0; i < 4; ++i) {
                const int src = qsl + 16 * (i >> 1);
                const int v0 = __shfl((int)wp[2 * g][i & 1], src);
                const int v1 = __shfl((int)wp[2 * g + 1][i & 1], src);
                pb.i[i] = (quad < 2) ? v0 : v1;
            }
            const bf16x8 vA0 = *(const bf16x8*)(vbase + g * 1024 + lo * 32 + quad * 8);
            const bf16x8 vA1 = *(const bf16x8*)(vbase + g * 1024 + (16 + lo) * 32 + quad * 8);
            O0 = __builtin_amdgcn_mfma_f32_16x16x32_bf16(vA0, pb.v, O0, 0, 0, 0);
            O1 = __builtin_amdgcn_mfma_f32_16x16x32_bf16(vA1, pb.v, O1, 0, 0, 0);
        }
    }

    // ---- the single causal chunk (owner: parity of n-1) ----
    if (((n - 1) & 1) == h) {
        const int kb = kstart + ((n - 1) << 6);

        f32x4 S[4];
        float4 fm4[4];
        const unsigned short* kp = kT + (size_t)(kb + lo) * C + quad * 8;
        #pragma unroll
        for (int t = 0; t < 4; ++t) {
            const bf16x8 kA = *(const bf16x8*)(kp + (size_t)(t * 16) * C);
            S[t] = __builtin_amdgcn_mfma_f32_16x16x32_bf16(kA, qB, zero, 0, 0, 0);
            fm4[t] = *(const float4*)(mask + kb + t * 16 + quad * 4);
        }

        unsigned wp[4][2];
        #pragma unroll
        for (int t = 0; t < 4; ++t) {
            const float* fmp = (const float*)&fm4[t];
            float p[4];
            #pragma unroll
            for (int r = 0; r < 4; ++r) {
                const int key = kb + t * 16 + quad * 4 + r;
                const float pd = (key <= myq) ? __expf(S[t][r]) * (fmp[r] + 1e-9f) : 0.f;
                psum += pd;
                p[r] = pd * fmp[r];
            }
            wp[t][0] = pk2(p[0], p[1]);
            wp[t][1] = pk2(p[2], p[3]);
        }

        const unsigned short* vbase = v2 + ((size_t)(kb >> 6) << 11);
        #pragma unroll
        for (int g = 0; g < 2; ++g) {
            union { int i[4]; bf16x8 v; } pb;
            #pragma unroll
            for (int i = 0; i < 4; ++i) {
                const int src = qsl + 16 * (i >> 1);
                const int v0 = __shfl((int)wp[2 * g][i & 1], src);
                const int v1 = __shfl((int)wp[2 * g + 1][i & 1], src);
                pb.i[i] = (quad < 2) ? v0 : v1;
            }
            const bf16x8 vA0 = *(const bf16x8*)(vbase + g * 1024 + lo * 32 + quad * 8);
            const bf16x8 vA1 = *(const bf16x8*)(vbase + g * 1024 + (16 + lo) * 32 + quad * 8);
            O0 = __builtin_amdgcn_mfma_f32_16x16x32_bf16(vA0, pb.v, O0, 0, 0, 0);
            O1 = __builtin_amdgcn_mfma_f32_16x16x32_bf16(vA1, pb.v, O1, 0, 0, 0);
        }
    }

    // ---- merge wave1 partials into wave0 ----
    if (h == 1) {
        #pragma unroll
        for (int r = 0; r < 4; ++r) {
            mrg[lane * 9 + r]     = O0[r];
            mrg[lane * 9 + 4 + r] = O1[r];
        }
        mrg[lane * 9 + 8] = psum;
    }
    __syncthreads();
    if (h == 1) return;

    #pragma unroll
    for (int r = 0; r < 4; ++r) {
        O0[r] += mrg[lane * 9 + r];
        O1[r] += mrg[lane * 9 + 4 + r];
    }
    psum += mrg[lane * 9 + 8];

    // ---- denominator across quads for each query col ----
    float dsum = psum;
    dsum += __shfl_xor(dsum, 16);
    dsum += __shfl_xor(dsum, 32);
    const float inv = 1.f / dsum;

    // ---- epilogue: T = relu(O^T*inv) -> B-layout via quad-permute ----
    unsigned tw[2][2];
    tw[0][0] = pk2(fmaxf(O0[0] * inv, 0.f), fmaxf(O0[1] * inv, 0.f));
    tw[0][1] = pk2(fmaxf(O0[2] * inv, 0.f), fmaxf(O0[3] * inv, 0.f));
    tw[1][0] = pk2(fmaxf(O1[0] * inv, 0.f), fmaxf(O1[1] * inv, 0.f));
    tw[1][1] = pk2(fmaxf(O1[2] * inv, 0.f), fmaxf(O1[3] * inv, 0.f));

    union { int i[4]; bf16x8 v; } tb;
    #pragma unroll
    for (int i = 0; i < 4; ++i) {
        const int src = qsl + 16 * (i >> 1);
        const int v0 = __shfl((int)tw[0][i & 1], src);
        const int v1 = __shfl((int)tw[1][i & 1], src);
        tb.i[i] = (quad < 2) ? v0 : v1;
    }

    const float mk = mask[myq];
    #pragma unroll
    for (int t = 0; t < 4; ++t) {
        float wtmp[8];
        *(float4*)&wtmp[0] = *(const float4*)(Wo + (size_t)(t * 16 + lo) * C + quad * 8);
        *(float4*)&wtmp[4] = *(const float4*)(Wo + (size_t)(t * 16 + lo) * C + quad * 8 + 4);
        union { unsigned u[4]; bf16x8 v; } wo;
        #pragma unroll
        for (int i = 0; i < 4; ++i) wo.u[i] = pk2(wtmp[2 * i], wtmp[2 * i + 1]);
        const f32x4 R = __builtin_amdgcn_mfma_f32_16x16x32_bf16(wo.v, tb.v, zero, 0, 0, 0);
        const float4 bo4 = *(const float4*)(bo + t * 16 + quad * 4);
        const float* bop = (const float*)&bo4;
        #pragma unroll
        for (int r = 0; r < 4; ++r)
            out[(size_t)(t * 16 + quad * 4 + r) * L + myq] = (R[r] + bop[r]) * mk;
    }
}

extern "C" void kernel_launch(void* const* d_in, const int* in_sizes, int n_in,
                              void* d_out, int out_size, void* d_ws, size_t ws_size,
                              hipStream_t stream)
{
    const float* x1   = (const float*)d_in[0];
    // d_in[1] = x2 : unused (encoder stage)
    const float* mask = (const float*)d_in[2];
    const float* Wq   = (const float*)d_in[3];
    const float* bq   = (const float*)d_in[4];
    const float* Wk   = (const float*)d_in[5];
    const float* bk   = (const float*)d_in[6];
    const float* Wv   = (const float*)d_in[7];
    const float* bv   = (const float*)d_in[8];
    const float* Wo   = (const float*)d_in[9];
    const float* bo   = (const float*)d_in[10];
    float* out = (float*)d_out;

    const int L = in_sizes[0] / QD;                  // 65536
    unsigned short* qT = (unsigned short*)d_ws;      // L*32 bf16
    unsigned short* kT = qT + (size_t)L * C;         // L*32 bf16
    unsigned short* v2 = kT + (size_t)L * C;         // L*32 bf16 (tiled)

    hipLaunchKernelGGL(qkv_proj, dim3(L / 256), dim3(256), 0, stream,
                       x1, Wq, bq, Wk, bk, Wv, bv, qT, kT, v2, L);

    // one wg per 16-query tile: L/16 = 4096 wgs (2 waves each, split-K)
    hipLaunchKernelGGL(att_kernel, dim3(L / 16), dim3(128), 0, stream,
                       qT, kT, v2, mask, Wo, bo, out, L);
}

// Round 4
// 146.077 us; speedup vs baseline: 1.4290x; 1.2214x over previous
//
#include <hip/hip_runtime.h>
#include <hip/hip_bf16.h>
#include <math.h>

#define C    32      // attention dim
#define QD   64      // x1 channels
#define VD   64      // output channels
#define BLK  512     // sliding window block length
#define HALF 256

typedef __attribute__((ext_vector_type(8))) short bf16x8;
typedef __attribute__((ext_vector_type(4))) float f32x4;

static __device__ inline unsigned short f2bf(float x) {
    union { float f; unsigned u; } v; v.f = x;
    unsigned r = v.u + 0x7FFFu + ((v.u >> 16) & 1u);   // RNE
    return (unsigned short)(r >> 16);
}

// pack 2 floats -> one dword holding 2 bf16 (low = a, high = b)
static __device__ inline unsigned pk2(float a, float b) {
    union { __hip_bfloat162 h; unsigned u; } x;
    x.h = __float22bfloat162_rn(make_float2(a, b));
    return x.u;
}

// ---------------- kernel 1: QKV projection ----------------
// R0 form: 3 dispatches via blockIdx.y, straight-line body -> VGPR=60, acc[]
// promoted, no scratch. DO NOT fuse the three kinds into one thread (R1:
// 96 live accs spilled at VGPR-cap 60, 96us) and DO NOT make kind a runtime
// loop (R3: SROA failed, acc[] to scratch, VGPR=32, 70us). The x1 triple
// read is ~5us of LLC-resident traffic — not worth touching.
// kind 0 -> qT bf16 (L,32) pre-scaled by 1/sqrt(32)
// kind 1 -> kT bf16 (L,32)
// kind 2 -> v2 bf16 tiled: [l>>6][(l>>5)&1][ch][l&31]  (2048 elems / 64-key block)
__global__ __launch_bounds__(256) void qkv_proj(
    const float* __restrict__ x1,
    const float* __restrict__ Wq, const float* __restrict__ bq,
    const float* __restrict__ Wk, const float* __restrict__ bk,
    const float* __restrict__ Wv, const float* __restrict__ bv,
    unsigned short* __restrict__ qT, unsigned short* __restrict__ kT,
    unsigned short* __restrict__ v2, int L)
{
    const int kind = blockIdx.y;
    const float* __restrict__ W = (kind == 0) ? Wq : ((kind == 1) ? Wk : Wv);
    const float* __restrict__ b = (kind == 0) ? bq : ((kind == 1) ? bk : bv);

    const int l = blockIdx.x * 256 + threadIdx.x;

    float acc[C];
    #pragma unroll
    for (int o = 0; o < C; ++o) acc[o] = 0.f;

    #pragma unroll 4
    for (int c = 0; c < QD; ++c) {
        const float x = x1[(size_t)c * L + l];       // coalesced
        #pragma unroll
        for (int o = 0; o < C; ++o)
            acc[o] = fmaf(W[o * QD + c], x, acc[o]); // W uniform -> s_load
    }

    if (kind == 2) {
        unsigned short* dst = v2 + ((size_t)(l >> 6) << 11) + (((l >> 5) & 1) << 10) + (l & 31);
        #pragma unroll
        for (int o = 0; o < C; ++o)
            dst[o << 5] = f2bf(acc[o] + b[o]);
    } else {
        const float s = (kind == 0) ? 0.17677669529663689f : 1.0f;
        unsigned short h[C];
        #pragma unroll
        for (int o = 0; o < C; ++o) h[o] = f2bf((acc[o] + b[o]) * s);
        unsigned short* base = ((kind == 0) ? qT : kT) + (size_t)l * C;
        uint4* dst = (uint4*)base;
        const uint4* src = (const uint4*)h;
        #pragma unroll
        for (int i = 0; i < 4; ++i) dst[i] = src[i];
    }
}

// ---------------- kernel 2: MFMA flash attention, split-K waves ----------
// wg = 128 thr = 2 waves covering the SAME 16 queries, alternate 64-key
// chunks (deferred-sum softmax is order-independent). LPT dispatch order,
// XCD-affine. Exactly one causal chunk per tile; full chunks have no
// compares and no clamps (index ranges proven in-bounds).
// Grid MUST be L/16 wgs (one per 16-query tile) — R5 launched half and failed.
// launch_bounds (128,4): R3 A/B vs R0 says (128,4) ~ (128,8) within noise;
// keeping (128,4) for register headroom.
__global__ __launch_bounds__(128, 4) void att_kernel(
    const unsigned short* __restrict__ qT,
    const unsigned short* __restrict__ kT,
    const unsigned short* __restrict__ v2,
    const float* __restrict__ mask,
    const float* __restrict__ Wo, const float* __restrict__ bo,
    float* __restrict__ out, int L)
{
    __shared__ float mrg[64 * 9];

    const int tid  = threadIdx.x;
    const int lane = tid & 63;
    const int h    = tid >> 6;          // wave parity within pair
    const int lo   = lane & 15;
    const int quad = lane >> 4;

    // LPT + XCD affinity: id = (31-s)*128 + w  ->  long waves first, id%8==w%8
    const int id = blockIdx.x;
    const int w  = id & 127;
    const int s  = 31 - (id >> 7);
    const int wq0 = w * BLK + s * 16;

    const int kstart = max(0, w * BLK - HALF);
    const int n      = ((wq0 + 15 - kstart) >> 6) + 1;   // total 64-key chunks
    const int myq    = wq0 + lo;

    // Q B-frag: B[k=c][n=q]
    const bf16x8 qB = *(const bf16x8*)(qT + (size_t)myq * C + quad * 8);

    const f32x4 zero = {0.f, 0.f, 0.f, 0.f};
    f32x4 O0 = zero, O1 = zero;
    float psum = 0.f;

    const int qsl = lo + 16 * ((quad & 1) << 1);

    // ---- full chunks (no causal masking) ----
    for (int j = h; j < n - 1; j += 2) {
        const int kb = kstart + (j << 6);

        f32x4 S[4];
        float4 fm4[4];
        const unsigned short* kp = kT + (size_t)(kb + lo) * C + quad * 8;
        #pragma unroll
        for (int t = 0; t < 4; ++t) {
            const bf16x8 kA = *(const bf16x8*)(kp + (size_t)(t * 16) * C);
            S[t] = __builtin_amdgcn_mfma_f32_16x16x32_bf16(kA, qB, zero, 0, 0, 0);
            fm4[t] = *(const float4*)(mask + kb + t * 16 + quad * 4);
        }

        unsigned wp[4][2];
        #pragma unroll
        for (int t = 0; t < 4; ++t) {
            const float* fmp = (const float*)&fm4[t];
            float p[4];
            #pragma unroll
            for (int r = 0; r < 4; ++r) {
                const float pd = __expf(S[t][r]) * (fmp[r] + 1e-9f);
                psum += pd;
                p[r] = pd * fmp[r];
            }
            wp[t][0] = pk2(p[0], p[1]);
            wp[t][1] = pk2(p[2], p[3]);
        }

        const unsigned short* vbase = v2 + ((size_t)(kb >> 6) << 11);
        #pragma unroll
        for (int g = 0; g < 2; ++g) {
            union { int i[4]; bf16x8 v; } pb;
            #pragma unroll
            for (int i = 0; i < 4; ++i) {
                const int src = qsl + 16 * (i >> 1);
                const int v0 = __shfl((int)wp[2 * g][i & 1], src);
                const int v1 = __shfl((int)wp[2 * g + 1][i & 1], src);
                pb.i[i] = (quad < 2) ? v0 : v1;
            }
            const bf16x8 vA0 = *(const bf16x8*)(vbase + g * 1024 + lo * 32 + quad * 8);
            const bf16x8 vA1 = *(const bf16x8*)(vbase + g * 1024 + (16 + lo) * 32 + quad * 8);
            O0 = __builtin_amdgcn_mfma_f32_16x16x32_bf16(vA0, pb.v, O0, 0, 0, 0);
            O1 = __builtin_amdgcn_mfma_f32_16x16x32_bf16(vA1, pb.v, O1, 0, 0, 0);
        }
    }

    // ---- the single causal chunk (owner: parity of n-1) ----
    if (((n - 1) & 1) == h) {
        const int kb = kstart + ((n - 1) << 6);

        f32x4 S[4];
        float4 fm4[4];
        const unsigned short* kp = kT + (size_t)(kb + lo) * C + quad * 8;
        #pragma unroll
        for (int t = 0; t < 4; ++t) {
            const bf16x8 kA = *(const bf16x8*)(kp + (size_t)(t * 16) * C);
            S[t] = __builtin_amdgcn_mfma_f32_16x16x32_bf16(kA, qB, zero, 0, 0, 0);
            fm4[t] = *(const float4*)(mask + kb + t * 16 + quad * 4);
        }

        unsigned wp[4][2];
        #pragma unroll
        for (int t = 0; t < 4; ++t) {
            const float* fmp = (const float*)&fm4[t];
            float p[4];
            #pragma unroll
            for (int r = 0; r < 4; ++r) {
                const int key = kb + t * 16 + quad * 4 + r;
                const float pd = (key <= myq) ? __expf(S[t][r]) * (fmp[r] + 1e-9f) : 0.f;
                psum += pd;
                p[r] = pd * fmp[r];
            }
            wp[t][0] = pk2(p[0], p[1]);
            wp[t][1] = pk2(p[2], p[3]);
        }

        const unsigned short* vbase = v2 + ((size_t)(kb >> 6) << 11);
        #pragma unroll
        for (int g = 0; g < 2; ++g) {
            union { int i[4]; bf16x8 v; } pb;
            #pragma unroll
            for (int i = 0; i < 4; ++i) {
                const int src = qsl + 16 * (i >> 1);
                const int v0 = __shfl((int)wp[2 * g][i & 1], src);
                const int v1 = __shfl((int)wp[2 * g + 1][i & 1], src);
                pb.i[i] = (quad < 2) ? v0 : v1;
            }
            const bf16x8 vA0 = *(const bf16x8*)(vbase + g * 1024 + lo * 32 + quad * 8);
            const bf16x8 vA1 = *(const bf16x8*)(vbase + g * 1024 + (16 + lo) * 32 + quad * 8);
            O0 = __builtin_amdgcn_mfma_f32_16x16x32_bf16(vA0, pb.v, O0, 0, 0, 0);
            O1 = __builtin_amdgcn_mfma_f32_16x16x32_bf16(vA1, pb.v, O1, 0, 0, 0);
        }
    }

    // ---- merge wave1 partials into wave0 ----
    if (h == 1) {
        #pragma unroll
        for (int r = 0; r < 4; ++r) {
            mrg[lane * 9 + r]     = O0[r];
            mrg[lane * 9 + 4 + r] = O1[r];
        }
        mrg[lane * 9 + 8] = psum;
    }
    __syncthreads();
    if (h == 1) return;

    #pragma unroll
    for (int r = 0; r < 4; ++r) {
        O0[r] += mrg[lane * 9 + r];
        O1[r] += mrg[lane * 9 + 4 + r];
    }
    psum += mrg[lane * 9 + 8];

    // ---- denominator across quads for each query col ----
    float dsum = psum;
    dsum += __shfl_xor(dsum, 16);
    dsum += __shfl_xor(dsum, 32);
    const float inv = 1.f / dsum;

    // ---- epilogue: T = relu(O^T*inv) -> B-layout via quad-permute ----
    unsigned tw[2][2];
    tw[0][0] = pk2(fmaxf(O0[0] * inv, 0.f), fmaxf(O0[1] * inv, 0.f));
    tw[0][1] = pk2(fmaxf(O0[2] * inv, 0.f), fmaxf(O0[3] * inv, 0.f));
    tw[1][0] = pk2(fmaxf(O1[0] * inv, 0.f), fmaxf(O1[1] * inv, 0.f));
    tw[1][1] = pk2(fmaxf(O1[2] * inv, 0.f), fmaxf(O1[3] * inv, 0.f));

    union { int i[4]; bf16x8 v; } tb;
    #pragma unroll
    for (int i = 0; i < 4; ++i) {
        const int src = qsl + 16 * (i >> 1);
        const int v0 = __shfl((int)tw[0][i & 1], src);
        const int v1 = __shfl((int)tw[1][i & 1], src);
        tb.i[i] = (quad < 2) ? v0 : v1;
    }

    const float mk = mask[myq];
    #pragma unroll
    for (int t = 0; t < 4; ++t) {
        float wtmp[8];
        *(float4*)&wtmp[0] = *(const float4*)(Wo + (size_t)(t * 16 + lo) * C + quad * 8);
        *(float4*)&wtmp[4] = *(const float4*)(Wo + (size_t)(t * 16 + lo) * C + quad * 8 + 4);
        union { unsigned u[4]; bf16x8 v; } wo;
        #pragma unroll
        for (int i = 0; i < 4; ++i) wo.u[i] = pk2(wtmp[2 * i], wtmp[2 * i + 1]);
        const f32x4 R = __builtin_amdgcn_mfma_f32_16x16x32_bf16(wo.v, tb.v, zero, 0, 0, 0);
        const float4 bo4 = *(const float4*)(bo + t * 16 + quad * 4);
        const float* bop = (const float*)&bo4;
        #pragma unroll
        for (int r = 0; r < 4; ++r)
            out[(size_t)(t * 16 + quad * 4 + r) * L + myq] = (R[r] + bop[r]) * mk;
    }
}

extern "C" void kernel_launch(void* const* d_in, const int* in_sizes, int n_in,
                              void* d_out, int out_size, void* d_ws, size_t ws_size,
                              hipStream_t stream)
{
    const float* x1   = (const float*)d_in[0];
    // d_in[1] = x2 : unused (encoder stage)
    const float* mask = (const float*)d_in[2];
    const float* Wq   = (const float*)d_in[3];
    const float* bq   = (const float*)d_in[4];
    const float* Wk   = (const float*)d_in[5];
    const float* bk   = (const float*)d_in[6];
    const float* Wv   = (const float*)d_in[7];
    const float* bv   = (const float*)d_in[8];
    const float* Wo   = (const float*)d_in[9];
    const float* bo   = (const float*)d_in[10];
    float* out = (float*)d_out;

    const int L = in_sizes[0] / QD;                  // 65536
    unsigned short* qT = (unsigned short*)d_ws;      // L*32 bf16
    unsigned short* kT = qT + (size_t)L * C;         // L*32 bf16
    unsigned short* v2 = kT + (size_t)L * C;         // L*32 bf16 (tiled)

    hipLaunchKernelGGL(qkv_proj, dim3(L / 256, 3), dim3(256), 0, stream,
                       x1, Wq, bq, Wk, bk, Wv, bv, qT, kT, v2, L);

    // one wg per 16-query tile: L/16 = 4096 wgs (2 waves each, split-K)
    hipLaunchKernelGGL(att_kernel, dim3(L / 16), dim3(128), 0, stream,
                       qT, kT, v2, mask, Wo, bo, out, L);
}

// Round 5
// 131.415 us; speedup vs baseline: 1.5884x; 1.1116x over previous
//
#include <hip/hip_runtime.h>
#include <hip/hip_bf16.h>
#include <math.h>

#define C    32      // attention dim
#define QD   64      // x1 channels
#define VD   64      // output channels
#define BLK  512     // sliding window block length
#define HALF 256

typedef __attribute__((ext_vector_type(8))) short bf16x8;
typedef __attribute__((ext_vector_type(4))) float f32x4;

static __device__ inline unsigned short f2bf(float x) {
    union { float f; unsigned u; } v; v.f = x;
    unsigned r = v.u + 0x7FFFu + ((v.u >> 16) & 1u);   // RNE
    return (unsigned short)(r >> 16);
}

// pack 2 floats -> one dword holding 2 bf16 (low = a, high = b)
static __device__ inline unsigned pk2(float a, float b) {
    union { __hip_bfloat162 h; unsigned u; } x;
    x.h = __float22bfloat162_rn(make_float2(a, b));
    return x.u;
}

// ---------------- kernel 1: QKV projection via MFMA ----------------
// R4 budget analysis: scalar-FMA qkv = ~38us wall (VALU/latency-bound at
// 1-3 waves/SIMD, 2048 FMA/thread). This is matmul-shaped (K=64) -> MFMA.
// O[32xL] = W[32x64] . x1[64xL] for all 3 kinds in ONE pass: the x1 B-frag
// is shared across q/k/v (x1 read once). Per wave: one 16-timestep tile,
// 12 MFMAs (3 kinds x 2 o-tiles x 2 k-chunks). W converted to A-frags once
// at start (L1-hot); q scale 1/sqrt(32) folded into Wq AND bq.
// Grid L/64 = 1024 wgs x 4 waves -> 4 wg/CU (16 waves/CU).
// History: R1 (96 fused f32 accs) spilled; R3 (runtime kind loop) broke
// SROA -> scratch. Here every array index is static after full unroll.
// Layouts consumed by att_kernel (unchanged):
//   qT bf16 (L,32) pre-scaled; kT bf16 (L,32);
//   v2 bf16 tiled: idx = ((l>>6)<<11) + (((l>>5)&1)<<10) + ch*32 + (l&31)
__global__ __launch_bounds__(256) void qkv_proj(
    const float* __restrict__ x1,
    const float* __restrict__ Wq, const float* __restrict__ bq,
    const float* __restrict__ Wk, const float* __restrict__ bk,
    const float* __restrict__ Wv, const float* __restrict__ bv,
    unsigned short* __restrict__ qT, unsigned short* __restrict__ kT,
    unsigned short* __restrict__ v2, int L)
{
    const int lane = threadIdx.x & 63;
    const int wv   = threadIdx.x >> 6;
    const int lo   = lane & 15;
    const int quad = lane >> 4;

    const int tile = blockIdx.x * 4 + wv;   // one 16-l tile per wave
    const int l    = tile * 16 + lo;

    // ---- B-frags: x1 in bf16. lane(lo,quad) holds x1[c=kc*32+quad*8+j][l]
    float xv[16];
    #pragma unroll
    for (int kc = 0; kc < 2; ++kc)
        #pragma unroll
        for (int j = 0; j < 8; ++j)
            xv[kc * 8 + j] = x1[(size_t)(kc * 32 + quad * 8 + j) * L + l];

    bf16x8 B[2];
    #pragma unroll
    for (int kc = 0; kc < 2; ++kc) {
        union { unsigned u[4]; bf16x8 v; } bb;
        #pragma unroll
        for (int p = 0; p < 4; ++p)
            bb.u[p] = pk2(xv[kc * 8 + 2 * p], xv[kc * 8 + 2 * p + 1]);
        B[kc] = bb.v;
    }

    // ---- A-frags: W in bf16. lane(lo,quad) = W[o=ot*16+lo][c=kc*32+quad*8+j]
    bf16x8 A[3][2][2];  // [kind][otile][kchunk] — static indices after unroll
    #pragma unroll
    for (int kind = 0; kind < 3; ++kind) {
        const float* __restrict__ Wp = (kind == 0) ? Wq : ((kind == 1) ? Wk : Wv);
        const float sc = (kind == 0) ? 0.17677669529663689f : 1.0f;
        #pragma unroll
        for (int ot = 0; ot < 2; ++ot) {
            #pragma unroll
            for (int kc = 0; kc < 2; ++kc) {
                const float* wp = Wp + (size_t)(ot * 16 + lo) * QD + kc * 32 + quad * 8;
                const float4 w0 = *(const float4*)wp;
                const float4 w1 = *(const float4*)(wp + 4);
                union { unsigned u[4]; bf16x8 v; } t;
                t.u[0] = pk2(w0.x * sc, w0.y * sc);
                t.u[1] = pk2(w0.z * sc, w0.w * sc);
                t.u[2] = pk2(w1.x * sc, w1.y * sc);
                t.u[3] = pk2(w1.z * sc, w1.w * sc);
                A[kind][ot][kc] = t.v;
            }
        }
    }

    // ---- 12 MFMAs: acc[kind][ot] over 2 k-chunks.
    // C/D layout: lane(lo,quad) reg r = O[o = ot*16 + quad*4 + r][l]
    const f32x4 zero = {0.f, 0.f, 0.f, 0.f};
    f32x4 acc[3][2];
    #pragma unroll
    for (int kind = 0; kind < 3; ++kind)
        #pragma unroll
        for (int ot = 0; ot < 2; ++ot) {
            f32x4 a = __builtin_amdgcn_mfma_f32_16x16x32_bf16(A[kind][ot][0], B[0], zero, 0, 0, 0);
            acc[kind][ot] = __builtin_amdgcn_mfma_f32_16x16x32_bf16(A[kind][ot][1], B[1], a, 0, 0, 0);
        }

    // ---- epilogue: bias + pack + store ----
    // q (scaled bias), k: row-major (L,32), 8B store per (lane, otile)
    #pragma unroll
    for (int kind = 0; kind < 2; ++kind) {
        const float* __restrict__ bp = (kind == 0) ? bq : bk;
        const float sc = (kind == 0) ? 0.17677669529663689f : 1.0f;
        unsigned short* __restrict__ dstT = (kind == 0) ? qT : kT;
        #pragma unroll
        for (int ot = 0; ot < 2; ++ot) {
            const float4 b4 = *(const float4*)(bp + ot * 16 + quad * 4);
            const float r0 = acc[kind][ot][0] + b4.x * sc;
            const float r1 = acc[kind][ot][1] + b4.y * sc;
            const float r2 = acc[kind][ot][2] + b4.z * sc;
            const float r3 = acc[kind][ot][3] + b4.w * sc;
            uint2 d;
            d.x = pk2(r0, r1);
            d.y = pk2(r2, r3);
            *(uint2*)(dstT + (size_t)l * C + ot * 16 + quad * 4) = d;
        }
    }
    // v: tiled layout, scalar short stores (o-stride 32)
    {
        const int vb = ((l >> 6) << 11) + (((l >> 5) & 1) << 10) + (l & 31);
        #pragma unroll
        for (int ot = 0; ot < 2; ++ot) {
            const float4 b4 = *(const float4*)(bv + ot * 16 + quad * 4);
            const float* bp4 = (const float*)&b4;
            #pragma unroll
            for (int r = 0; r < 4; ++r)
                v2[vb + (ot * 16 + quad * 4 + r) * 32] = f2bf(acc[2][ot][r] + bp4[r]);
        }
    }
}

// ---------------- kernel 2: MFMA flash attention, split-K waves ----------
// wg = 128 thr = 2 waves covering the SAME 16 queries, alternate 64-key
// chunks (deferred-sum softmax is order-independent). LPT dispatch order,
// XCD-affine. Exactly one causal chunk per tile; full chunks have no
// compares and no clamps (index ranges proven in-bounds).
// Grid MUST be L/16 wgs (one per 16-query tile) — R5 launched half and failed.
// launch_bounds (128,4): R4 A/B vs R0 says (128,4) ~ (128,8) within noise;
// keeping (128,4) for register headroom.
__global__ __launch_bounds__(128, 4) void att_kernel(
    const unsigned short* __restrict__ qT,
    const unsigned short* __restrict__ kT,
    const unsigned short* __restrict__ v2,
    const float* __restrict__ mask,
    const float* __restrict__ Wo, const float* __restrict__ bo,
    float* __restrict__ out, int L)
{
    __shared__ float mrg[64 * 9];

    const int tid  = threadIdx.x;
    const int lane = tid & 63;
    const int h    = tid >> 6;          // wave parity within pair
    const int lo   = lane & 15;
    const int quad = lane >> 4;

    // LPT + XCD affinity: id = (31-s)*128 + w  ->  long waves first, id%8==w%8
    const int id = blockIdx.x;
    const int w  = id & 127;
    const int s  = 31 - (id >> 7);
    const int wq0 = w * BLK + s * 16;

    const int kstart = max(0, w * BLK - HALF);
    const int n      = ((wq0 + 15 - kstart) >> 6) + 1;   // total 64-key chunks
    const int myq    = wq0 + lo;

    // Q B-frag: B[k=c][n=q]
    const bf16x8 qB = *(const bf16x8*)(qT + (size_t)myq * C + quad * 8);

    const f32x4 zero = {0.f, 0.f, 0.f, 0.f};
    f32x4 O0 = zero, O1 = zero;
    float psum = 0.f;

    const int qsl = lo + 16 * ((quad & 1) << 1);

    // ---- full chunks (no causal masking) ----
    for (int j = h; j < n - 1; j += 2) {
        const int kb = kstart + (j << 6);

        f32x4 S[4];
        float4 fm4[4];
        const unsigned short* kp = kT + (size_t)(kb + lo) * C + quad * 8;
        #pragma unroll
        for (int t = 0; t < 4; ++t) {
            const bf16x8 kA = *(const bf16x8*)(kp + (size_t)(t * 16) * C);
            S[t] = __builtin_amdgcn_mfma_f32_16x16x32_bf16(kA, qB, zero, 0, 0, 0);
            fm4[t] = *(const float4*)(mask + kb + t * 16 + quad * 4);
        }

        unsigned wp[4][2];
        #pragma unroll
        for (int t = 0; t < 4; ++t) {
            const float* fmp = (const float*)&fm4[t];
            float p[4];
            #pragma unroll
            for (int r = 0; r < 4; ++r) {
                const float pd = __expf(S[t][r]) * (fmp[r] + 1e-9f);
                psum += pd;
                p[r] = pd * fmp[r];
            }
            wp[t][0] = pk2(p[0], p[1]);
            wp[t][1] = pk2(p[2], p[3]);
        }

        const unsigned short* vbase = v2 + ((size_t)(kb >> 6) << 11);
        #pragma unroll
        for (int g = 0; g < 2; ++g) {
            union { int i[4]; bf16x8 v; } pb;
            #pragma unroll
            for (int i = 0; i < 4; ++i) {
                const int src = qsl + 16 * (i >> 1);
                const int v0 = __shfl((int)wp[2 * g][i & 1], src);
                const int v1 = __shfl((int)wp[2 * g + 1][i & 1], src);
                pb.i[i] = (quad < 2) ? v0 : v1;
            }
            const bf16x8 vA0 = *(const bf16x8*)(vbase + g * 1024 + lo * 32 + quad * 8);
            const bf16x8 vA1 = *(const bf16x8*)(vbase + g * 1024 + (16 + lo) * 32 + quad * 8);
            O0 = __builtin_amdgcn_mfma_f32_16x16x32_bf16(vA0, pb.v, O0, 0, 0, 0);
            O1 = __builtin_amdgcn_mfma_f32_16x16x32_bf16(vA1, pb.v, O1, 0, 0, 0);
        }
    }

    // ---- the single causal chunk (owner: parity of n-1) ----
    if (((n - 1) & 1) == h) {
        const int kb = kstart + ((n - 1) << 6);

        f32x4 S[4];
        float4 fm4[4];
        const unsigned short* kp = kT + (size_t)(kb + lo) * C + quad * 8;
        #pragma unroll
        for (int t = 0; t < 4; ++t) {
            const bf16x8 kA = *(const bf16x8*)(kp + (size_t)(t * 16) * C);
            S[t] = __builtin_amdgcn_mfma_f32_16x16x32_bf16(kA, qB, zero, 0, 0, 0);
            fm4[t] = *(const float4*)(mask + kb + t * 16 + quad * 4);
        }

        unsigned wp[4][2];
        #pragma unroll
        for (int t = 0; t < 4; ++t) {
            const float* fmp = (const float*)&fm4[t];
            float p[4];
            #pragma unroll
            for (int r = 0; r < 4; ++r) {
                const int key = kb + t * 16 + quad * 4 + r;
                const float pd = (key <= myq) ? __expf(S[t][r]) * (fmp[r] + 1e-9f) : 0.f;
                psum += pd;
                p[r] = pd * fmp[r];
            }
            wp[t][0] = pk2(p[0], p[1]);
            wp[t][1] = pk2(p[2], p[3]);
        }

        const unsigned short* vbase = v2 + ((size_t)(kb >> 6) << 11);
        #pragma unroll
        for (int g = 0; g < 2; ++g) {
            union { int i[4]; bf16x8 v; } pb;
            #pragma unroll
            for (int i = 0; i < 4; ++i) {
                const int src = qsl + 16 * (i >> 1);
                const int v0 = __shfl((int)wp[2 * g][i & 1], src);
                const int v1 = __shfl((int)wp[2 * g + 1][i & 1], src);
                pb.i[i] = (quad < 2) ? v0 : v1;
            }
            const bf16x8 vA0 = *(const bf16x8*)(vbase + g * 1024 + lo * 32 + quad * 8);
            const bf16x8 vA1 = *(const bf16x8*)(vbase + g * 1024 + (16 + lo) * 32 + quad * 8);
            O0 = __builtin_amdgcn_mfma_f32_16x16x32_bf16(vA0, pb.v, O0, 0, 0, 0);
            O1 = __builtin_amdgcn_mfma_f32_16x16x32_bf16(vA1, pb.v, O1, 0, 0, 0);
        }
    }

    // ---- merge wave1 partials into wave0 ----
    if (h == 1) {
        #pragma unroll
        for (int r = 0; r < 4; ++r) {
            mrg[lane * 9 + r]     = O0[r];
            mrg[lane * 9 + 4 + r] = O1[r];
        }
        mrg[lane * 9 + 8] = psum;
    }
    __syncthreads();
    if (h == 1) return;

    #pragma unroll
    for (int r = 0; r < 4; ++r) {
        O0[r] += mrg[lane * 9 + r];
        O1[r] += mrg[lane * 9 + 4 + r];
    }
    psum += mrg[lane * 9 + 8];

    // ---- denominator across quads for each query col ----
    float dsum = psum;
    dsum += __shfl_xor(dsum, 16);
    dsum += __shfl_xor(dsum, 32);
    const float inv = 1.f / dsum;

    // ---- epilogue: T = relu(O^T*inv) -> B-layout via quad-permute ----
    unsigned tw[2][2];
    tw[0][0] = pk2(fmaxf(O0[0] * inv, 0.f), fmaxf(O0[1] * inv, 0.f));
    tw[0][1] = pk2(fmaxf(O0[2] * inv, 0.f), fmaxf(O0[3] * inv, 0.f));
    tw[1][0] = pk2(fmaxf(O1[0] * inv, 0.f), fmaxf(O1[1] * inv, 0.f));
    tw[1][1] = pk2(fmaxf(O1[2] * inv, 0.f), fmaxf(O1[3] * inv, 0.f));

    union { int i[4]; bf16x8 v; } tb;
    #pragma unroll
    for (int i = 0; i < 4; ++i) {
        const int src = qsl + 16 * (i >> 1);
        const int v0 = __shfl((int)tw[0][i & 1], src);
        const int v1 = __shfl((int)tw[1][i & 1], src);
        tb.i[i] = (quad < 2) ? v0 : v1;
    }

    const float mk = mask[myq];
    #pragma unroll
    for (int t = 0; t < 4; ++t) {
        float wtmp[8];
        *(float4*)&wtmp[0] = *(const float4*)(Wo + (size_t)(t * 16 + lo) * C + quad * 8);
        *(float4*)&wtmp[4] = *(const float4*)(Wo + (size_t)(t * 16 + lo) * C + quad * 8 + 4);
        union { unsigned u[4]; bf16x8 v; } wo;
        #pragma unroll
        for (int i = 0; i < 4; ++i) wo.u[i] = pk2(wtmp[2 * i], wtmp[2 * i + 1]);
        const f32x4 R = __builtin_amdgcn_mfma_f32_16x16x32_bf16(wo.v, tb.v, zero, 0, 0, 0);
        const float4 bo4 = *(const float4*)(bo + t * 16 + quad * 4);
        const float* bop = (const float*)&bo4;
        #pragma unroll
        for (int r = 0; r < 4; ++r)
            out[(size_t)(t * 16 + quad * 4 + r) * L + myq] = (R[r] + bop[r]) * mk;
    }
}

extern "C" void kernel_launch(void* const* d_in, const int* in_sizes, int n_in,
                              void* d_out, int out_size, void* d_ws, size_t ws_size,
                              hipStream_t stream)
{
    const float* x1   = (const float*)d_in[0];
    // d_in[1] = x2 : unused (encoder stage)
    const float* mask = (const float*)d_in[2];
    const float* Wq   = (const float*)d_in[3];
    const float* bq   = (const float*)d_in[4];
    const float* Wk   = (const float*)d_in[5];
    const float* bk   = (const float*)d_in[6];
    const float* Wv   = (const float*)d_in[7];
    const float* bv   = (const float*)d_in[8];
    const float* Wo   = (const float*)d_in[9];
    const float* bo   = (const float*)d_in[10];
    float* out = (float*)d_out;

    const int L = in_sizes[0] / QD;                  // 65536
    unsigned short* qT = (unsigned short*)d_ws;      // L*32 bf16
    unsigned short* kT = qT + (size_t)L * C;         // L*32 bf16
    unsigned short* v2 = kT + (size_t)L * C;         // L*32 bf16 (tiled)

    // MFMA qkv: 64 timesteps per wg (4 waves x 16) -> L/64 = 1024 wgs
    hipLaunchKernelGGL(qkv_proj, dim3(L / 64), dim3(256), 0, stream,
                       x1, Wq, bq, Wk, bk, Wv, bv, qT, kT, v2, L);

    // one wg per 16-query tile: L/16 = 4096 wgs (2 waves each, split-K)
    hipLaunchKernelGGL(att_kernel, dim3(L / 16), dim3(128), 0, stream,
                       qT, kT, v2, mask, Wo, bo, out, L);
}

// Round 6
// 130.975 us; speedup vs baseline: 1.5937x; 1.0034x over previous
//
#include <hip/hip_runtime.h>
#include <hip/hip_bf16.h>
#include <math.h>

#define C    32      // attention dim
#define QD   64      // x1 channels
#define VD   64      // output channels
#define BLK  512     // sliding window block length
#define HALF 256

typedef __attribute__((ext_vector_type(8))) short bf16x8;
typedef __attribute__((ext_vector_type(4))) float f32x4;

static __device__ inline unsigned short f2bf(float x) {
    union { float f; unsigned u; } v; v.f = x;
    unsigned r = v.u + 0x7FFFu + ((v.u >> 16) & 1u);   // RNE
    return (unsigned short)(r >> 16);
}

// pack 2 floats -> one dword holding 2 bf16 (low = a, high = b)
static __device__ inline unsigned pk2(float a, float b) {
    union { __hip_bfloat162 h; unsigned u; } x;
    x.h = __float22bfloat162_rn(make_float2(a, b));
    return x.u;
}

// ---------------- kernel 1: QKV projection via MFMA + LDS-staged stores ----
// R5 post-mortem: MFMA qkv = ~23us, 5x above the ~4.6us traffic floor at
// only 1.3 TB/s effective -> STORE-bound theory: qT/kT stores have 64B
// lane stride (8B per 64B line per instr) and v2 uses 2B scalar scatter:
// 12 scatter-store instrs/lane for 12.6 MB. Fix: the wg's 64 timesteps map
// to exactly one contiguous 4KB region in EACH of qT/kT/v2 (v2 tile by
// construction) -> stage in LDS (12KB/wg), barrier, write 3 coalesced
// uint4 stores/thread (1KB/instr/wave). LDS scatter conflicts (~8-way on
// 2-4B writes) cost ~17cy/instr vs global 64-segment scatter.
// History: R1 fused-96-acc spill; R3 runtime-kind SROA failure; R5 MFMA
// structure (kept): W A-frags converted per wave, q-scale folded into Wq/bq.
// Layouts consumed by att_kernel (unchanged):
//   qT bf16 (L,32) pre-scaled; kT bf16 (L,32);
//   v2 bf16 tiled: idx = ((l>>6)<<11) + (((l>>5)&1)<<10) + ch*32 + (l&31)
__global__ __launch_bounds__(256) void qkv_proj(
    const float* __restrict__ x1,
    const float* __restrict__ Wq, const float* __restrict__ bq,
    const float* __restrict__ Wk, const float* __restrict__ bk,
    const float* __restrict__ Wv, const float* __restrict__ bv,
    unsigned short* __restrict__ qT, unsigned short* __restrict__ kT,
    unsigned short* __restrict__ v2, int L)
{
    __shared__ uint4 lq[256], lk[256], lv[256];   // 3 x 4KB

    const int lane = threadIdx.x & 63;
    const int wv   = threadIdx.x >> 6;
    const int lo   = lane & 15;
    const int quad = lane >> 4;

    const int tile = blockIdx.x * 4 + wv;   // one 16-l tile per wave
    const int l    = tile * 16 + lo;
    const int ll   = wv * 16 + lo;          // l offset within the wg's 64-l block

    // ---- B-frags: x1 in bf16. lane(lo,quad) holds x1[c=kc*32+quad*8+j][l]
    float xv[16];
    #pragma unroll
    for (int kc = 0; kc < 2; ++kc)
        #pragma unroll
        for (int j = 0; j < 8; ++j)
            xv[kc * 8 + j] = x1[(size_t)(kc * 32 + quad * 8 + j) * L + l];

    bf16x8 B[2];
    #pragma unroll
    for (int kc = 0; kc < 2; ++kc) {
        union { unsigned u[4]; bf16x8 v; } bb;
        #pragma unroll
        for (int p = 0; p < 4; ++p)
            bb.u[p] = pk2(xv[kc * 8 + 2 * p], xv[kc * 8 + 2 * p + 1]);
        B[kc] = bb.v;
    }

    // ---- A-frags: W in bf16. lane(lo,quad) = W[o=ot*16+lo][c=kc*32+quad*8+j]
    bf16x8 A[3][2][2];  // [kind][otile][kchunk] — static indices after unroll
    #pragma unroll
    for (int kind = 0; kind < 3; ++kind) {
        const float* __restrict__ Wp = (kind == 0) ? Wq : ((kind == 1) ? Wk : Wv);
        const float sc = (kind == 0) ? 0.17677669529663689f : 1.0f;
        #pragma unroll
        for (int ot = 0; ot < 2; ++ot) {
            #pragma unroll
            for (int kc = 0; kc < 2; ++kc) {
                const float* wp = Wp + (size_t)(ot * 16 + lo) * QD + kc * 32 + quad * 8;
                const float4 w0 = *(const float4*)wp;
                const float4 w1 = *(const float4*)(wp + 4);
                union { unsigned u[4]; bf16x8 v; } t;
                t.u[0] = pk2(w0.x * sc, w0.y * sc);
                t.u[1] = pk2(w0.z * sc, w0.w * sc);
                t.u[2] = pk2(w1.x * sc, w1.y * sc);
                t.u[3] = pk2(w1.z * sc, w1.w * sc);
                A[kind][ot][kc] = t.v;
            }
        }
    }

    // ---- 12 MFMAs: acc[kind][ot] over 2 k-chunks.
    // C/D layout: lane(lo,quad) reg r = O[o = ot*16 + quad*4 + r][l]
    const f32x4 zero = {0.f, 0.f, 0.f, 0.f};
    f32x4 acc[3][2];
    #pragma unroll
    for (int kind = 0; kind < 3; ++kind)
        #pragma unroll
        for (int ot = 0; ot < 2; ++ot) {
            f32x4 a = __builtin_amdgcn_mfma_f32_16x16x32_bf16(A[kind][ot][0], B[0], zero, 0, 0, 0);
            acc[kind][ot] = __builtin_amdgcn_mfma_f32_16x16x32_bf16(A[kind][ot][1], B[1], a, 0, 0, 0);
        }

    // ---- stage bias+pack into LDS (scatter lands in LDS, not L2) ----
    // q/k: row-major [64][32] shorts == [64][16] dwords
    #pragma unroll
    for (int kind = 0; kind < 2; ++kind) {
        const float* __restrict__ bp = (kind == 0) ? bq : bk;
        const float sc = (kind == 0) ? 0.17677669529663689f : 1.0f;
        unsigned* __restrict__ ld = (unsigned*)((kind == 0) ? lq : lk);
        #pragma unroll
        for (int ot = 0; ot < 2; ++ot) {
            const float4 b4 = *(const float4*)(bp + ot * 16 + quad * 4);
            const float r0 = acc[kind][ot][0] + b4.x * sc;
            const float r1 = acc[kind][ot][1] + b4.y * sc;
            const float r2 = acc[kind][ot][2] + b4.z * sc;
            const float r3 = acc[kind][ot][3] + b4.w * sc;
            ld[ll * 16 + ot * 8 + quad * 2 + 0] = pk2(r0, r1);
            ld[ll * 16 + ot * 8 + quad * 2 + 1] = pk2(r2, r3);
        }
    }
    // v: tiled [ll>=32][ch][ll&31] shorts
    {
        unsigned short* __restrict__ lvs = (unsigned short*)lv;
        const int vb = ((ll >> 5) << 10) + ((ll & 31) - 0);   // + ch*32 below
        #pragma unroll
        for (int ot = 0; ot < 2; ++ot) {
            const float4 b4 = *(const float4*)(bv + ot * 16 + quad * 4);
            const float* bp4 = (const float*)&b4;
            #pragma unroll
            for (int r = 0; r < 4; ++r)
                lvs[vb + (ot * 16 + quad * 4 + r) * 32] = f2bf(acc[2][ot][r] + bp4[r]);
        }
    }

    __syncthreads();

    // ---- coalesced write-out: each thread 3x uint4 (1KB/instr/wave) ----
    const int t = threadIdx.x;
    const size_t blk16 = (size_t)blockIdx.x * 256;   // uint4 index of this wg's 4KB block
    ((uint4*)qT)[blk16 + t] = lq[t];
    ((uint4*)kT)[blk16 + t] = lk[t];
    ((uint4*)v2)[blk16 + t] = lv[t];
}

// ---------------- kernel 2: MFMA flash attention, split-K waves ----------
// wg = 128 thr = 2 waves covering the SAME 16 queries, alternate 64-key
// chunks (deferred-sum softmax is order-independent). LPT dispatch order,
// XCD-affine. Exactly one causal chunk per tile; full chunks have no
// compares and no clamps (index ranges proven in-bounds).
// Grid MUST be L/16 wgs (one per 16-query tile) — R5 launched half and failed.
// launch_bounds (128,4): R4 A/B vs R0 says (128,4) ~ (128,8) within noise;
// keeping (128,4) for register headroom.
__global__ __launch_bounds__(128, 4) void att_kernel(
    const unsigned short* __restrict__ qT,
    const unsigned short* __restrict__ kT,
    const unsigned short* __restrict__ v2,
    const float* __restrict__ mask,
    const float* __restrict__ Wo, const float* __restrict__ bo,
    float* __restrict__ out, int L)
{
    __shared__ float mrg[64 * 9];

    const int tid  = threadIdx.x;
    const int lane = tid & 63;
    const int h    = tid >> 6;          // wave parity within pair
    const int lo   = lane & 15;
    const int quad = lane >> 4;

    // LPT + XCD affinity: id = (31-s)*128 + w  ->  long waves first, id%8==w%8
    const int id = blockIdx.x;
    const int w  = id & 127;
    const int s  = 31 - (id >> 7);
    const int wq0 = w * BLK + s * 16;

    const int kstart = max(0, w * BLK - HALF);
    const int n      = ((wq0 + 15 - kstart) >> 6) + 1;   // total 64-key chunks
    const int myq    = wq0 + lo;

    // Q B-frag: B[k=c][n=q]
    const bf16x8 qB = *(const bf16x8*)(qT + (size_t)myq * C + quad * 8);

    const f32x4 zero = {0.f, 0.f, 0.f, 0.f};
    f32x4 O0 = zero, O1 = zero;
    float psum = 0.f;

    const int qsl = lo + 16 * ((quad & 1) << 1);

    // ---- full chunks (no causal masking) ----
    for (int j = h; j < n - 1; j += 2) {
        const int kb = kstart + (j << 6);

        f32x4 S[4];
        float4 fm4[4];
        const unsigned short* kp = kT + (size_t)(kb + lo) * C + quad * 8;
        #pragma unroll
        for (int t = 0; t < 4; ++t) {
            const bf16x8 kA = *(const bf16x8*)(kp + (size_t)(t * 16) * C);
            S[t] = __builtin_amdgcn_mfma_f32_16x16x32_bf16(kA, qB, zero, 0, 0, 0);
            fm4[t] = *(const float4*)(mask + kb + t * 16 + quad * 4);
        }

        unsigned wp[4][2];
        #pragma unroll
        for (int t = 0; t < 4; ++t) {
            const float* fmp = (const float*)&fm4[t];
            float p[4];
            #pragma unroll
            for (int r = 0; r < 4; ++r) {
                const float pd = __expf(S[t][r]) * (fmp[r] + 1e-9f);
                psum += pd;
                p[r] = pd * fmp[r];
            }
            wp[t][0] = pk2(p[0], p[1]);
            wp[t][1] = pk2(p[2], p[3]);
        }

        const unsigned short* vbase = v2 + ((size_t)(kb >> 6) << 11);
        #pragma unroll
        for (int g = 0; g < 2; ++g) {
            union { int i[4]; bf16x8 v; } pb;
            #pragma unroll
            for (int i = 0; i < 4; ++i) {
                const int src = qsl + 16 * (i >> 1);
                const int v0 = __shfl((int)wp[2 * g][i & 1], src);
                const int v1 = __shfl((int)wp[2 * g + 1][i & 1], src);
                pb.i[i] = (quad < 2) ? v0 : v1;
            }
            const bf16x8 vA0 = *(const bf16x8*)(vbase + g * 1024 + lo * 32 + quad * 8);
            const bf16x8 vA1 = *(const bf16x8*)(vbase + g * 1024 + (16 + lo) * 32 + quad * 8);
            O0 = __builtin_amdgcn_mfma_f32_16x16x32_bf16(vA0, pb.v, O0, 0, 0, 0);
            O1 = __builtin_amdgcn_mfma_f32_16x16x32_bf16(vA1, pb.v, O1, 0, 0, 0);
        }
    }

    // ---- the single causal chunk (owner: parity of n-1) ----
    if (((n - 1) & 1) == h) {
        const int kb = kstart + ((n - 1) << 6);

        f32x4 S[4];
        float4 fm4[4];
        const unsigned short* kp = kT + (size_t)(kb + lo) * C + quad * 8;
        #pragma unroll
        for (int t = 0; t < 4; ++t) {
            const bf16x8 kA = *(const bf16x8*)(kp + (size_t)(t * 16) * C);
            S[t] = __builtin_amdgcn_mfma_f32_16x16x32_bf16(kA, qB, zero, 0, 0, 0);
            fm4[t] = *(const float4*)(mask + kb + t * 16 + quad * 4);
        }

        unsigned wp[4][2];
        #pragma unroll
        for (int t = 0; t < 4; ++t) {
            const float* fmp = (const float*)&fm4[t];
            float p[4];
            #pragma unroll
            for (int r = 0; r < 4; ++r) {
                const int key = kb + t * 16 + quad * 4 + r;
                const float pd = (key <= myq) ? __expf(S[t][r]) * (fmp[r] + 1e-9f) : 0.f;
                psum += pd;
                p[r] = pd * fmp[r];
            }
            wp[t][0] = pk2(p[0], p[1]);
            wp[t][1] = pk2(p[2], p[3]);
        }

        const unsigned short* vbase = v2 + ((size_t)(kb >> 6) << 11);
        #pragma unroll
        for (int g = 0; g < 2; ++g) {
            union { int i[4]; bf16x8 v; } pb;
            #pragma unroll
            for (int i = 0; i < 4; ++i) {
                const int src = qsl + 16 * (i >> 1);
                const int v0 = __shfl((int)wp[2 * g][i & 1], src);
                const int v1 = __shfl((int)wp[2 * g + 1][i & 1], src);
                pb.i[i] = (quad < 2) ? v0 : v1;
            }
            const bf16x8 vA0 = *(const bf16x8*)(vbase + g * 1024 + lo * 32 + quad * 8);
            const bf16x8 vA1 = *(const bf16x8*)(vbase + g * 1024 + (16 + lo) * 32 + quad * 8);
            O0 = __builtin_amdgcn_mfma_f32_16x16x32_bf16(vA0, pb.v, O0, 0, 0, 0);
            O1 = __builtin_amdgcn_mfma_f32_16x16x32_bf16(vA1, pb.v, O1, 0, 0, 0);
        }
    }

    // ---- merge wave1 partials into wave0 ----
    if (h == 1) {
        #pragma unroll
        for (int r = 0; r < 4; ++r) {
            mrg[lane * 9 + r]     = O0[r];
            mrg[lane * 9 + 4 + r] = O1[r];
        }
        mrg[lane * 9 + 8] = psum;
    }
    __syncthreads();
    if (h == 1) return;

    #pragma unroll
    for (int r = 0; r < 4; ++r) {
        O0[r] += mrg[lane * 9 + r];
        O1[r] += mrg[lane * 9 + 4 + r];
    }
    psum += mrg[lane * 9 + 8];

    // ---- denominator across quads for each query col ----
    float dsum = psum;
    dsum += __shfl_xor(dsum, 16);
    dsum += __shfl_xor(dsum, 32);
    const float inv = 1.f / dsum;

    // ---- epilogue: T = relu(O^T*inv) -> B-layout via quad-permute ----
    unsigned tw[2][2];
    tw[0][0] = pk2(fmaxf(O0[0] * inv, 0.f), fmaxf(O0[1] * inv, 0.f));
    tw[0][1] = pk2(fmaxf(O0[2] * inv, 0.f), fmaxf(O0[3] * inv, 0.f));
    tw[1][0] = pk2(fmaxf(O1[0] * inv, 0.f), fmaxf(O1[1] * inv, 0.f));
    tw[1][1] = pk2(fmaxf(O1[2] * inv, 0.f), fmaxf(O1[3] * inv, 0.f));

    union { int i[4]; bf16x8 v; } tb;
    #pragma unroll
    for (int i = 0; i < 4; ++i) {
        const int src = qsl + 16 * (i >> 1);
        const int v0 = __shfl((int)tw[0][i & 1], src);
        const int v1 = __shfl((int)tw[1][i & 1], src);
        tb.i[i] = (quad < 2) ? v0 : v1;
    }

    const float mk = mask[myq];
    #pragma unroll
    for (int t = 0; t < 4; ++t) {
        float wtmp[8];
        *(float4*)&wtmp[0] = *(const float4*)(Wo + (size_t)(t * 16 + lo) * C + quad * 8);
        *(float4*)&wtmp[4] = *(const float4*)(Wo + (size_t)(t * 16 + lo) * C + quad * 8 + 4);
        union { unsigned u[4]; bf16x8 v; } wo;
        #pragma unroll
        for (int i = 0; i < 4; ++i) wo.u[i] = pk2(wtmp[2 * i], wtmp[2 * i + 1]);
        const f32x4 R = __builtin_amdgcn_mfma_f32_16x16x32_bf16(wo.v, tb.v, zero, 0, 0, 0);
        const float4 bo4 = *(const float4*)(bo + t * 16 + quad * 4);
        const float* bop = (const float*)&bo4;
        #pragma unroll
        for (int r = 0; r < 4; ++r)
            out[(size_t)(t * 16 + quad * 4 + r) * L + myq] = (R[r] + bop[r]) * mk;
    }
}

extern "C" void kernel_launch(void* const* d_in, const int* in_sizes, int n_in,
                              void* d_out, int out_size, void* d_ws, size_t ws_size,
                              hipStream_t stream)
{
    const float* x1   = (const float*)d_in[0];
    // d_in[1] = x2 : unused (encoder stage)
    const float* mask = (const float*)d_in[2];
    const float* Wq   = (const float*)d_in[3];
    const float* bq   = (const float*)d_in[4];
    const float* Wk   = (const float*)d_in[5];
    const float* bk   = (const float*)d_in[6];
    const float* Wv   = (const float*)d_in[7];
    const float* bv   = (const float*)d_in[8];
    const float* Wo   = (const float*)d_in[9];
    const float* bo   = (const float*)d_in[10];
    float* out = (float*)d_out;

    const int L = in_sizes[0] / QD;                  // 65536
    unsigned short* qT = (unsigned short*)d_ws;      // L*32 bf16
    unsigned short* kT = qT + (size_t)L * C;         // L*32 bf16
    unsigned short* v2 = kT + (size_t)L * C;         // L*32 bf16 (tiled)

    // MFMA qkv: 64 timesteps per wg (4 waves x 16) -> L/64 = 1024 wgs
    hipLaunchKernelGGL(qkv_proj, dim3(L / 64), dim3(256), 0, stream,
                       x1, Wq, bq, Wk, bk, Wv, bv, qT, kT, v2, L);

    // one wg per 16-query tile: L/16 = 4096 wgs (2 waves each, split-K)
    hipLaunchKernelGGL(att_kernel, dim3(L / 16), dim3(128), 0, stream,
                       qT, kT, v2, mask, Wo, bo, out, L);
}